// Round 21
// baseline (341.311 us; speedup 1.0000x reference)
//
#include <hip/hip_runtime.h>
#include <hip/hip_bf16.h>
#include <math.h>

#define B_ 8
#define T_ 12
#define N_ 500
#define D_ 64
#define K_ 20
#define M_ (B_*T_)              // 96
#define MND_ 3072000            // M_*N_*D_

// workspace layout (float units)
#define XSB_OFF 0ul                         // 6 slices x MND ushort = 3*MND f
#define XTB_OFF (3ul*MND_)                  // XT ping-pong buf B: 3145728 f
#define AT_HI_OFF (5ul*MND_)                // 2*512*512 ushort = 262144 f
#define XT_OFF    (AT_HI_OFF + 262144ul)    // XT buf A: 3145728 f
#define WCT_OFF   (XT_OFF + 3145728ul)
#define WDT_OFF   (WCT_OFF + 32768ul)
#define BC_OFF    (WDT_OFF + 32768ul)
#define BD_OFF    (BC_OFF + 1024ul)

using f4 = __attribute__((ext_vector_type(4))) float;
typedef __attribute__((ext_vector_type(8))) short bf16x8;
typedef __attribute__((ext_vector_type(8))) short short8;
typedef __attribute__((ext_vector_type(4))) float f32x4;

__device__ inline ushort to_bf16u(float v) {
    __hip_bfloat16 b = __float2bfloat16(v);
    return *reinterpret_cast<ushort*>(&b);
}

// fast tanh: 1 - 2/(e^{2x}+1)
__device__ inline float fast_tanh(float x) {
    float u = __expf(2.0f * x);
    return 1.0f - 2.0f * __builtin_amdgcn_rcpf(u + 1.0f);
}

// ---------------- K1: fuse head-mixture weights ----------------
__global__ __launch_bounds__(256) void fuse_weights(
        const float* __restrict__ aw, const float* __restrict__ Bw,
        const float* __restrict__ ab, const float* __restrict__ Bb,
        float* __restrict__ bc, float* __restrict__ bd,
        ushort* __restrict__ wct, ushort* __restrict__ wdt) {
    int e = blockIdx.x * 256 + threadIdx.x;
    if (e < 131072) {
        int dd = e & 4095; int l = (e >> 12) & 1; int r = (e >> 13) & 7; int cd = e >> 16;
        float s = 0.f;
        #pragma unroll
        for (int h = 0; h < 4; ++h)
            s += aw[((cd*8 + r)*4 + h)*2 + l] * Bw[(h*2 + l)*4096 + dd];
        int tidx = (r*2 + l)*4096 + (dd & 63)*64 + (dd >> 6);
        (cd ? wdt : wct)[tidx] = to_bf16u(s);
    } else {
        int e2 = e - 131072;
        if (e2 < 2048) {
            int d = e2 & 63; int l = (e2 >> 6) & 1; int r = (e2 >> 7) & 7; int cd = e2 >> 10;
            float s = 0.f;
            #pragma unroll
            for (int h = 0; h < 4; ++h)
                s += ab[((cd*8 + r)*4 + h)*2 + l] * Bb[(h*2 + l)*64 + d];
            (cd ? bd : bc)[(r*2 + l)*64 + d] = s;
        }
    }
}

// ---------------- K2: [B,D,N,T] -> [M,N,D] transpose, bf16 out, coalesced v2 ----------------
// Block = (i, b, 8-node tile); 1008 blocks. Load mapping: consecutive LANES
// get consecutive p along the contiguous (n,t) axis (runs of 96 floats =
// 384B) — fixes r18's bug where lanes spanned d. LDS [96][65]: stride-65
// banks conflict-free both phases. Store: 128B-contiguous bf16 rows.
__global__ __launch_bounds__(256) void transpose_in(
        const float* __restrict__ x0, const float* __restrict__ x1,
        ushort* __restrict__ xsb0) {
    int bid = blockIdx.x;               // i*504 + b*63 + tile
    int tile = bid % 63;
    int b = (bid / 63) % 8;
    int i = bid / 504;
    int n0 = tile * 8;
    const float* __restrict__ x = i ? x1 : x0;
    ushort* __restrict__ xbo = xsb0 + (size_t)i * MND_;
    int tid = threadIdx.x;

    __shared__ float tile_s[96][65];

    const float* __restrict__ src = x + (size_t)b * 64 * 6000 + (size_t)n0 * 12;
    int lim = 6000 - n0 * 12;           // valid p per d-row (48 at last tile)
    #pragma unroll
    for (int it = 0; it < 24; ++it) {
        int e = it * 256 + tid;         // 0..6143
        int d = e / 96, p = e % 96;     // consecutive lanes -> consecutive p
        tile_s[p][d] = (p < lim) ? src[(size_t)d * 6000 + p] : 0.f;
    }
    __syncthreads();

    int row4 = tid >> 6;                // wave id 0..3
    int lane = tid & 63;
    #pragma unroll
    for (int it = 0; it < 24; ++it) {
        int p = it * 4 + row4;          // 0..95
        int nn = p / 12, t = p % 12;
        if (n0 + nn < N_)
            xbo[(((size_t)b * T_ + t) * N_ + (n0 + nn)) * D_ + lane] = to_bf16u(tile_s[p][lane]);
    }
}

// ---------------- K3a: adjT bf16 prep ----------------
__global__ __launch_bounds__(256) void adj_prep(
        const float* __restrict__ graphs,
        ushort* __restrict__ AT_hi) {
    int t = blockIdx.z;
    int n0 = blockIdx.x * 32, mm0 = blockIdx.y * 32;
    __shared__ float tile[32][33];
    int cc = threadIdx.x & 31, rr = threadIdx.x >> 5;
    #pragma unroll
    for (int it = 0; it < 4; ++it) {
        int n = n0 + it * 8 + rr, mm = mm0 + cc;
        tile[it * 8 + rr][cc] = (n < N_ && mm < N_)
            ? graphs[(size_t)t * 250000 + (size_t)n * 500 + mm] : 0.f;
    }
    __syncthreads();
    #pragma unroll
    for (int it = 0; it < 4; ++it) {
        int mml = it * 8 + rr, nl = cc;
        size_t idx = (size_t)t * 262144 + (size_t)(mm0 + mml) * 512 + n0 + nl;
        AT_hi[idx] = to_bf16u(tile[nl][mml]);
    }
}

// ---------------- K3b: XT(A) from XSB stage-0 — ushort transpose ----------------
__global__ __launch_bounds__(256) void xt_cast(
        const ushort* __restrict__ xsb,
        ushort* __restrict__ XT) {
    int i = blockIdx.z, m = blockIdx.y, c = blockIdx.x;
    int n0 = c * 64;
    __shared__ ushort tile[64][65];
    int d = threadIdx.x & 63, r4 = threadIdx.x >> 6;
    const ushort* __restrict__ src = xsb + (size_t)i * MND_ + (size_t)m * 32000;
    #pragma unroll
    for (int it = 0; it < 16; ++it) {
        int nl = it * 4 + r4; int n = n0 + nl;
        tile[nl][d] = (n < N_) ? src[(size_t)n * 64 + d] : (ushort)0;
    }
    __syncthreads();
    size_t base = (size_t)(i * 96 + m) * 64 * 512 + n0;
    int dl = threadIdx.x >> 2, ng = threadIdx.x & 3;
    #pragma unroll
    for (int half = 0; half < 2; ++half) {
        int nlb = ng * 16 + half * 8;
        short8 hv;
        #pragma unroll
        for (int q = 0; q < 8; ++q) hv[q] = (short)tile[nlb + q][dl];
        *(short8*)(XT + base + (size_t)dl * 512 + nlb) = hv;
    }
}

// ---------------- K3+4 fused: aggregate (per-wave cmb) -> LDS -> combine ----------------
__global__ __launch_bounds__(256) void agg_combine_mfma(
        const ushort* __restrict__ ATh, const ushort* __restrict__ XT,
        const ushort* __restrict__ wct, const ushort* __restrict__ wdt,
        const float* __restrict__ bcv, const float* __restrict__ bdv,
        ushort* __restrict__ xsb_out, ushort* __restrict__ xt_out,
        int l, int write_xt) {
    const int rt = blockIdx.x;
    const int m = blockIdx.y;
    const int n0 = rt * 64;
    const int tid = threadIdx.x;
    const int w = tid >> 6;
    const int lane = tid & 63;
    const int lr = lane & 15;
    const int lk = (lane >> 4) * 8;

    __shared__ ushort aggL[4][64][72];   // 36 KB

    // ---- phase 1: aggregate cmb = w ----
    {
        const int t = w >> 1, j = w & 1;
        const ushort* __restrict__ A_h = ATh + (size_t)t * 262144 + (size_t)(n0 + lr) * 512 + lk;
        const ushort* __restrict__ Bx  = XT + ((size_t)(j * 96 + m) * 64 + lr) * 512 + lk;
        f32x4 acc[4][4] = {};
        for (int k0 = 0; k0 < 512; k0 += 32) {
            bf16x8 ah[4], bh[4];
            #pragma unroll
            for (int f = 0; f < 4; ++f) {
                ah[f] = *(const bf16x8*)(A_h + (size_t)f * 8192 + k0);
                bh[f] = *(const bf16x8*)(Bx  + (size_t)f * 8192 + k0);
            }
            #pragma unroll
            for (int fi = 0; fi < 4; ++fi)
                #pragma unroll
                for (int fj = 0; fj < 4; ++fj)
                    acc[fi][fj] = __builtin_amdgcn_mfma_f32_16x16x32_bf16(ah[fi], bh[fj], acc[fi][fj], 0, 0, 0);
        }
        #pragma unroll
        for (int fi = 0; fi < 4; ++fi)
            #pragma unroll
            for (int reg = 0; reg < 4; ++reg) {
                int row = fi * 16 + (lane >> 4) * 4 + reg;
                #pragma unroll
                for (int fj = 0; fj < 4; ++fj)
                    aggL[w][row][fj * 16 + lr] = to_bf16u(acc[fi][fj][reg]);
            }
    }
    __syncthreads();

    // ---- phase 2: combine i = w>>1, row half = w&1 ----
    const int iw = w >> 1;
    const int r0l = (w & 1) * 32;
    f32x4 hacc[2][4] = {};

    for (int t = 0; t < 2; ++t) {
        #pragma unroll
        for (int j = 0; j < 2; ++j) {
            const int rel = (t * 2 + iw) * 2 + j;
            const int wb = (rel * 2 + l) * 4096;
            const ushort* __restrict__ Wc = wct + wb + lr * 64 + lk;
            const ushort* __restrict__ AjL = &aggL[t * 2 + j][r0l + lr][lk];

            f32x4 cacc[2][4];
            #pragma unroll
            for (int fj = 0; fj < 4; ++fj) {
                float bv = bcv[(rel * 2 + l) * 64 + fj * 16 + lr];
                #pragma unroll
                for (int fi = 0; fi < 2; ++fi) cacc[fi][fj] = f32x4{bv, bv, bv, bv};
            }

            if (j != iw) {
                const ushort* __restrict__ AiL = &aggL[t * 2 + iw][r0l + lr][lk];
                const ushort* __restrict__ Wd = wdt + wb + lr * 64 + lk;
                f32x4 dacc[2][4];
                #pragma unroll
                for (int fj = 0; fj < 4; ++fj) {
                    float bv = bdv[(rel * 2 + l) * 64 + fj * 16 + lr];
                    #pragma unroll
                    for (int fi = 0; fi < 2; ++fi) dacc[fi][fj] = f32x4{bv, bv, bv, bv};
                }
                #pragma unroll
                for (int k0 = 0; k0 < 64; k0 += 32) {
                    bf16x8 ajh[2], nih[2], wcf[4], wdf[4];
                    #pragma unroll
                    for (int fi = 0; fi < 2; ++fi) {
                        ajh[fi] = *(const bf16x8*)(AjL + fi * 16 * 72 + k0);
                        bf16x8 ih = *(const bf16x8*)(AiL + fi * 16 * 72 + k0);
                        #pragma unroll
                        for (int q = 0; q < 8; ++q) nih[fi][q] = ih[q] ^ (short)0x8000;
                    }
                    #pragma unroll
                    for (int fj = 0; fj < 4; ++fj) {
                        wcf[fj] = *(const bf16x8*)(Wc + fj * 1024 + k0);
                        wdf[fj] = *(const bf16x8*)(Wd + fj * 1024 + k0);
                    }
                    #pragma unroll
                    for (int fi = 0; fi < 2; ++fi)
                        #pragma unroll
                        for (int fj = 0; fj < 4; ++fj) {
                            cacc[fi][fj] = __builtin_amdgcn_mfma_f32_16x16x32_bf16(ajh[fi], wcf[fj], cacc[fi][fj], 0, 0, 0);
                            dacc[fi][fj] = __builtin_amdgcn_mfma_f32_16x16x32_bf16(ajh[fi], wdf[fj], dacc[fi][fj], 0, 0, 0);
                            dacc[fi][fj] = __builtin_amdgcn_mfma_f32_16x16x32_bf16(nih[fi], wdf[fj], dacc[fi][fj], 0, 0, 0);
                        }
                }
                #pragma unroll
                for (int fi = 0; fi < 2; ++fi)
                    #pragma unroll
                    for (int fj = 0; fj < 4; ++fj)
                        #pragma unroll
                        for (int reg = 0; reg < 4; ++reg) {
                            hacc[fi][fj][reg] += fmaxf(cacc[fi][fj][reg], 0.f);
                            hacc[fi][fj][reg] += fast_tanh(dacc[fi][fj][reg]);
                        }
            } else {
                #pragma unroll
                for (int k0 = 0; k0 < 64; k0 += 32) {
                    bf16x8 ajh[2], wcf[4];
                    #pragma unroll
                    for (int fi = 0; fi < 2; ++fi)
                        ajh[fi] = *(const bf16x8*)(AjL + fi * 16 * 72 + k0);
                    #pragma unroll
                    for (int fj = 0; fj < 4; ++fj)
                        wcf[fj] = *(const bf16x8*)(Wc + fj * 1024 + k0);
                    #pragma unroll
                    for (int fi = 0; fi < 2; ++fi)
                        #pragma unroll
                        for (int fj = 0; fj < 4; ++fj)
                            cacc[fi][fj] = __builtin_amdgcn_mfma_f32_16x16x32_bf16(ajh[fi], wcf[fj], cacc[fi][fj], 0, 0, 0);
                }
                #pragma unroll
                for (int fj = 0; fj < 4; ++fj) {
                    float tb = fast_tanh(bdv[(rel * 2 + l) * 64 + fj * 16 + lr]);
                    #pragma unroll
                    for (int fi = 0; fi < 2; ++fi)
                        #pragma unroll
                        for (int reg = 0; reg < 4; ++reg) {
                            hacc[fi][fj][reg] += fmaxf(cacc[fi][fj][reg], 0.f);
                            hacc[fi][fj][reg] += tb;
                        }
                }
            }
        }
    }
    __syncthreads();   // all phase-2 LDS reads done; aggL reusable

    // ---- phase 3: transposed epilogue via LDS overlay ----
    float* stg = ((float*)aggL) + w * 2080;   // 32 x 65 fp32 per wave
    #pragma unroll
    for (int fi = 0; fi < 2; ++fi)
        #pragma unroll
        for (int reg = 0; reg < 4; ++reg) {
            int rloc = fi * 16 + (lane >> 4) * 4 + reg;
            bool ok = (n0 + r0l + rloc) < N_;
            #pragma unroll
            for (int fj = 0; fj < 4; ++fj)
                stg[rloc * 65 + fj * 16 + lr] = ok ? hacc[fi][fj][reg] : 0.f;
        }
    // same-wave LDS raw: ds ops in-order per wave
    ushort* __restrict__ Xb = xsb_out + (size_t)iw * MND_;
    int gbase = m * 500 + n0 + r0l;
    #pragma unroll
    for (int q = 0; q < 32; ++q) {
        if (n0 + r0l + q < N_)
            Xb[(size_t)(gbase + q) * 64 + lane] = to_bf16u(stg[q * 65 + lane]);
    }
    if (write_xt) {
        size_t tb = ((size_t)(iw * 96 + m) * 64 + lane) * 512 + n0 + r0l;
        #pragma unroll
        for (int g2 = 0; g2 < 4; ++g2) {
            short8 hv;
            #pragma unroll
            for (int q = 0; q < 8; ++q)
                hv[q] = (short)to_bf16u(stg[(g2 * 8 + q) * 65 + lane]);
            *(short8*)(xt_out + tb + g2 * 8) = hv;
        }
    }
}

// ---------------- K5: summarize — pair-channel gather, bf16 staging, div-free flush ----------------
__global__ __launch_bounds__(192) void summarize(
        const ushort* __restrict__ XSB, const int* __restrict__ nbr,
        const float* __restrict__ nw, float* __restrict__ out) {
    int wg = (blockIdx.x & 7) * 252 + (blockIdx.x >> 3);
    int grp = wg / 126;
    int rem = wg % 126;
    int i = grp >> 3, b = grp & 7;
    int l = rem / 42;
    int rem2 = rem % 42;
    int t = rem2 / 21;
    int tile = rem2 % 21;
    int n0 = tile * 24;
    int tid = threadIdx.x;
    int g6 = tid >> 5;           // node group 0..5
    int d2 = tid & 31;           // channel pair

    __shared__ int    nb_s[24][20];
    __shared__ float  w_s[24][20];
    __shared__ ushort staged[64][145];   // 18.6 KB bf16

    for (int e = tid; e < 480; e += 192) {
        int nn = e / 20, k = e % 20;
        int n = n0 + nn;
        nb_s[nn][k] = (n < N_) ? nbr[((size_t)t * N_ + n) * K_ + k] : 0;
        w_s[nn][k]  = (n < N_) ? nw[((size_t)t * N_ + n) * K_ + k] : 0.f;
    }
    __syncthreads();

    // div-free flush constants: e(m,r) = 576m + 192r + tid -> c2 = 4m + f_r, q = g_r
    int f0 = tid / 144,           g0 = tid % 144;
    int f1 = (192 + tid) / 144,   g1 = (192 + tid) % 144;
    int f2 = (384 + tid) / 144,   g2v = (384 + tid) % 144;

    const uint* __restrict__ Xbase = (const uint*)(XSB + ((size_t)l * 2 + i) * MND_
                                     + (size_t)b * T_ * N_ * D_) + d2;
    size_t obase = ((size_t)((i * 8 + b) * 384 + t * 192 + l * 64)) * 6000
                 + (size_t)n0 * 12;

    #pragma unroll
    for (int half = 0; half < 2; ++half) {
        #pragma unroll
        for (int nn2 = 0; nn2 < 2; ++nn2) {
            int pl = g6 * 2 + nn2;
            int nl = half * 12 + pl;
            #pragma unroll
            for (int tt0 = 0; tt0 < 12; tt0 += 4) {
                const uint* __restrict__ Xm0 = Xbase + (size_t)(tt0 + 0) * 16000;
                const uint* __restrict__ Xm1 = Xbase + (size_t)(tt0 + 1) * 16000;
                const uint* __restrict__ Xm2 = Xbase + (size_t)(tt0 + 2) * 16000;
                const uint* __restrict__ Xm3 = Xbase + (size_t)(tt0 + 3) * 16000;
                float a0l = 0.f, a0h = 0.f, a1l = 0.f, a1h = 0.f;
                float a2l = 0.f, a2h = 0.f, a3l = 0.f, a3h = 0.f;
                #pragma unroll
                for (int k = 0; k < K_; ++k) {
                    size_t off = (size_t)nb_s[nl][k] * 32;
                    float w = w_s[nl][k];
                    uint u0 = Xm0[off], u1 = Xm1[off], u2 = Xm2[off], u3 = Xm3[off];
                    a0l = fmaf(__uint_as_float(u0 << 16), w, a0l);
                    a0h = fmaf(__uint_as_float(u0 & 0xffff0000u), w, a0h);
                    a1l = fmaf(__uint_as_float(u1 << 16), w, a1l);
                    a1h = fmaf(__uint_as_float(u1 & 0xffff0000u), w, a1h);
                    a2l = fmaf(__uint_as_float(u2 << 16), w, a2l);
                    a2h = fmaf(__uint_as_float(u2 & 0xffff0000u), w, a2h);
                    a3l = fmaf(__uint_as_float(u3 << 16), w, a3l);
                    a3h = fmaf(__uint_as_float(u3 & 0xffff0000u), w, a3h);
                }
                int p = pl * 12 + tt0;
                staged[2 * d2 + 0][p + 0] = to_bf16u(a0l);  staged[2 * d2 + 1][p + 0] = to_bf16u(a0h);
                staged[2 * d2 + 0][p + 1] = to_bf16u(a1l);  staged[2 * d2 + 1][p + 1] = to_bf16u(a1h);
                staged[2 * d2 + 0][p + 2] = to_bf16u(a2l);  staged[2 * d2 + 1][p + 2] = to_bf16u(a2h);
                staged[2 * d2 + 0][p + 3] = to_bf16u(a3l);  staged[2 * d2 + 1][p + 3] = to_bf16u(a3h);
            }
        }
        __syncthreads();
        int base_n = n0 + half * 12;
        int plim = (N_ - base_n) * 12;
        if (plim > 144) plim = 144;
        if (plim > 0) {
            #pragma unroll
            for (int mg = 0; mg < 16; ++mg) {
                if (g0 < plim)
                    out[obase + (size_t)(4 * mg + f0) * 6000 + (size_t)half * 144 + g0] =
                        __uint_as_float((uint)staged[4 * mg + f0][g0] << 16);
                if (g1 < plim)
                    out[obase + (size_t)(4 * mg + f1) * 6000 + (size_t)half * 144 + g1] =
                        __uint_as_float((uint)staged[4 * mg + f1][g1] << 16);
                if (g2v < plim)
                    out[obase + (size_t)(4 * mg + f2) * 6000 + (size_t)half * 144 + g2v] =
                        __uint_as_float((uint)staged[4 * mg + f2][g2v] << 16);
            }
        }
        __syncthreads();
    }
}

extern "C" void kernel_launch(void* const* d_in, const int* in_sizes, int n_in,
                              void* d_out, int out_size, void* d_ws, size_t ws_size,
                              hipStream_t stream) {
    const float* x0     = (const float*)d_in[0];
    const float* x1     = (const float*)d_in[1];
    const float* graphs = (const float*)d_in[2];
    const int*   nbr    = (const int*)d_in[3];
    const float* nwt    = (const float*)d_in[4];
    const float* aw     = (const float*)d_in[5];
    const float* Bw     = (const float*)d_in[6];
    const float* ab     = (const float*)d_in[7];
    const float* Bb     = (const float*)d_in[8];
    float* out = (float*)d_out;
    float* ws  = (float*)d_ws;

    ushort* XSB = (ushort*)(ws + XSB_OFF);
    ushort* XTb = (ushort*)(ws + XTB_OFF);
    ushort* ATh = (ushort*)(ws + AT_HI_OFF);
    ushort* XTa = (ushort*)(ws + XT_OFF);
    ushort* WCT = (ushort*)(ws + WCT_OFF);
    ushort* WDT = (ushort*)(ws + WDT_OFF);
    float*  BC  = ws + BC_OFF;
    float*  BD  = ws + BD_OFF;

    fuse_weights<<<520, 256, 0, stream>>>(aw, Bw, ab, Bb, BC, BD, WCT, WDT);
    transpose_in<<<1008, 256, 0, stream>>>(x0, x1, XSB);
    adj_prep<<<dim3(16, 16, 2), 256, 0, stream>>>(graphs, ATh);
    xt_cast<<<dim3(8, 96, 2), 256, 0, stream>>>(XSB, XTa);
    agg_combine_mfma<<<dim3(8, 96), 256, 0, stream>>>(
        ATh, XTa, WCT, WDT, BC, BD, XSB + 2ul * MND_, XTb, 0, 1);
    agg_combine_mfma<<<dim3(8, 96), 256, 0, stream>>>(
        ATh, XTb, WCT, WDT, BC, BD, XSB + 4ul * MND_, XTb, 1, 0);
    summarize<<<2016, 192, 0, stream>>>(XSB, nbr, nwt, out);
}

// Round 22
// 287.954 us; speedup vs baseline: 1.1853x; 1.1853x over previous
//
#include <hip/hip_runtime.h>
#include <hip/hip_bf16.h>
#include <math.h>

#define B_ 8
#define T_ 12
#define N_ 500
#define D_ 64
#define K_ 20
#define M_ (B_*T_)              // 96
#define MND_ 3072000            // M_*N_*D_

// workspace layout (float units)
#define XSB_OFF 0ul                         // 6 slices x MND ushort = 3*MND f
#define XTB_OFF (3ul*MND_)                  // XT ping-pong buf B: 3145728 f
#define AT_HI_OFF (5ul*MND_)                // 2*512*512 ushort = 262144 f
#define XT_OFF    (AT_HI_OFF + 262144ul)    // XT buf A: 3145728 f
#define WCT_OFF   (XT_OFF + 3145728ul)
#define WDT_OFF   (WCT_OFF + 32768ul)
#define BC_OFF    (WDT_OFF + 32768ul)
#define BD_OFF    (BC_OFF + 1024ul)

using f4 = __attribute__((ext_vector_type(4))) float;
typedef __attribute__((ext_vector_type(8))) short bf16x8;
typedef __attribute__((ext_vector_type(8))) short short8;
typedef __attribute__((ext_vector_type(4))) float f32x4;

__device__ inline ushort to_bf16u(float v) {
    __hip_bfloat16 b = __float2bfloat16(v);
    return *reinterpret_cast<ushort*>(&b);
}

// fast tanh: 1 - 2/(e^{2x}+1)
__device__ inline float fast_tanh(float x) {
    float u = __expf(2.0f * x);
    return 1.0f - 2.0f * __builtin_amdgcn_rcpf(u + 1.0f);
}

// ---------------- K1: fuse head-mixture weights ----------------
__global__ __launch_bounds__(256) void fuse_weights(
        const float* __restrict__ aw, const float* __restrict__ Bw,
        const float* __restrict__ ab, const float* __restrict__ Bb,
        float* __restrict__ bc, float* __restrict__ bd,
        ushort* __restrict__ wct, ushort* __restrict__ wdt) {
    int e = blockIdx.x * 256 + threadIdx.x;
    if (e < 131072) {
        int dd = e & 4095; int l = (e >> 12) & 1; int r = (e >> 13) & 7; int cd = e >> 16;
        float s = 0.f;
        #pragma unroll
        for (int h = 0; h < 4; ++h)
            s += aw[((cd*8 + r)*4 + h)*2 + l] * Bw[(h*2 + l)*4096 + dd];
        int tidx = (r*2 + l)*4096 + (dd & 63)*64 + (dd >> 6);
        (cd ? wdt : wct)[tidx] = to_bf16u(s);
    } else {
        int e2 = e - 131072;
        if (e2 < 2048) {
            int d = e2 & 63; int l = (e2 >> 6) & 1; int r = (e2 >> 7) & 7; int cd = e2 >> 10;
            float s = 0.f;
            #pragma unroll
            for (int h = 0; h < 4; ++h)
                s += ab[((cd*8 + r)*4 + h)*2 + l] * Bb[(h*2 + l)*64 + d];
            (cd ? bd : bc)[(r*2 + l)*64 + d] = s;
        }
    }
}

// ---------------- K2: [B,D,N,T] -> [M,N,D] transpose, bf16 out (round-17/20 proven) ----------------
__global__ __launch_bounds__(256) void transpose_in(
        const float* __restrict__ x0, const float* __restrict__ x1,
        ushort* __restrict__ xsb0) {
    int bid = blockIdx.x;
    int n = bid % N_; int b = (bid / N_) % B_; int i = bid / (N_ * B_);
    const float* __restrict__ x = i ? x1 : x0;
    ushort* __restrict__ xbo = xsb0 + (size_t)i * MND_;
    __shared__ float tile[64][13];
    #pragma unroll
    for (int q = 0; q < 3; ++q) {
        int e = q * 256 + threadIdx.x;
        int d = e / 12, t = e % 12;
        tile[d][t] = x[(((size_t)b * D_ + d) * N_ + n) * T_ + t];
    }
    __syncthreads();
    #pragma unroll
    for (int q = 0; q < 3; ++q) {
        int e = q * 256 + threadIdx.x;
        int t = e >> 6, d = e & 63;
        xbo[(((size_t)b * T_ + t) * N_ + n) * D_ + d] = to_bf16u(tile[d][t]);
    }
}

// ---------------- K3a: adjT bf16 prep ----------------
__global__ __launch_bounds__(256) void adj_prep(
        const float* __restrict__ graphs,
        ushort* __restrict__ AT_hi) {
    int t = blockIdx.z;
    int n0 = blockIdx.x * 32, mm0 = blockIdx.y * 32;
    __shared__ float tile[32][33];
    int cc = threadIdx.x & 31, rr = threadIdx.x >> 5;
    #pragma unroll
    for (int it = 0; it < 4; ++it) {
        int n = n0 + it * 8 + rr, mm = mm0 + cc;
        tile[it * 8 + rr][cc] = (n < N_ && mm < N_)
            ? graphs[(size_t)t * 250000 + (size_t)n * 500 + mm] : 0.f;
    }
    __syncthreads();
    #pragma unroll
    for (int it = 0; it < 4; ++it) {
        int mml = it * 8 + rr, nl = cc;
        size_t idx = (size_t)t * 262144 + (size_t)(mm0 + mml) * 512 + n0 + nl;
        AT_hi[idx] = to_bf16u(tile[nl][mml]);
    }
}

// ---------------- K3b: XT(A) from XSB stage-0 — ushort transpose ----------------
__global__ __launch_bounds__(256) void xt_cast(
        const ushort* __restrict__ xsb,
        ushort* __restrict__ XT) {
    int i = blockIdx.z, m = blockIdx.y, c = blockIdx.x;
    int n0 = c * 64;
    __shared__ ushort tile[64][65];
    int d = threadIdx.x & 63, r4 = threadIdx.x >> 6;
    const ushort* __restrict__ src = xsb + (size_t)i * MND_ + (size_t)m * 32000;
    #pragma unroll
    for (int it = 0; it < 16; ++it) {
        int nl = it * 4 + r4; int n = n0 + nl;
        tile[nl][d] = (n < N_) ? src[(size_t)n * 64 + d] : (ushort)0;
    }
    __syncthreads();
    size_t base = (size_t)(i * 96 + m) * 64 * 512 + n0;
    int dl = threadIdx.x >> 2, ng = threadIdx.x & 3;
    #pragma unroll
    for (int half = 0; half < 2; ++half) {
        int nlb = ng * 16 + half * 8;
        short8 hv;
        #pragma unroll
        for (int q = 0; q < 8; ++q) hv[q] = (short)tile[nlb + q][dl];
        *(short8*)(XT + base + (size_t)dl * 512 + nlb) = hv;
    }
}

// ---------------- K3+4 fused: aggregate (per-wave cmb) -> LDS -> combine ----------------
__global__ __launch_bounds__(256) void agg_combine_mfma(
        const ushort* __restrict__ ATh, const ushort* __restrict__ XT,
        const ushort* __restrict__ wct, const ushort* __restrict__ wdt,
        const float* __restrict__ bcv, const float* __restrict__ bdv,
        ushort* __restrict__ xsb_out, ushort* __restrict__ xt_out,
        int l, int write_xt) {
    const int rt = blockIdx.x;
    const int m = blockIdx.y;
    const int n0 = rt * 64;
    const int tid = threadIdx.x;
    const int w = tid >> 6;
    const int lane = tid & 63;
    const int lr = lane & 15;
    const int lk = (lane >> 4) * 8;

    __shared__ ushort aggL[4][64][72];   // 36 KB

    // ---- phase 1: aggregate cmb = w ----
    {
        const int t = w >> 1, j = w & 1;
        const ushort* __restrict__ A_h = ATh + (size_t)t * 262144 + (size_t)(n0 + lr) * 512 + lk;
        const ushort* __restrict__ Bx  = XT + ((size_t)(j * 96 + m) * 64 + lr) * 512 + lk;
        f32x4 acc[4][4] = {};
        for (int k0 = 0; k0 < 512; k0 += 32) {
            bf16x8 ah[4], bh[4];
            #pragma unroll
            for (int f = 0; f < 4; ++f) {
                ah[f] = *(const bf16x8*)(A_h + (size_t)f * 8192 + k0);
                bh[f] = *(const bf16x8*)(Bx  + (size_t)f * 8192 + k0);
            }
            #pragma unroll
            for (int fi = 0; fi < 4; ++fi)
                #pragma unroll
                for (int fj = 0; fj < 4; ++fj)
                    acc[fi][fj] = __builtin_amdgcn_mfma_f32_16x16x32_bf16(ah[fi], bh[fj], acc[fi][fj], 0, 0, 0);
        }
        #pragma unroll
        for (int fi = 0; fi < 4; ++fi)
            #pragma unroll
            for (int reg = 0; reg < 4; ++reg) {
                int row = fi * 16 + (lane >> 4) * 4 + reg;
                #pragma unroll
                for (int fj = 0; fj < 4; ++fj)
                    aggL[w][row][fj * 16 + lr] = to_bf16u(acc[fi][fj][reg]);
            }
    }
    __syncthreads();

    // ---- phase 2: combine i = w>>1, row half = w&1 ----
    const int iw = w >> 1;
    const int r0l = (w & 1) * 32;
    f32x4 hacc[2][4] = {};

    for (int t = 0; t < 2; ++t) {
        #pragma unroll
        for (int j = 0; j < 2; ++j) {
            const int rel = (t * 2 + iw) * 2 + j;
            const int wb = (rel * 2 + l) * 4096;
            const ushort* __restrict__ Wc = wct + wb + lr * 64 + lk;
            const ushort* __restrict__ AjL = &aggL[t * 2 + j][r0l + lr][lk];

            f32x4 cacc[2][4];
            #pragma unroll
            for (int fj = 0; fj < 4; ++fj) {
                float bv = bcv[(rel * 2 + l) * 64 + fj * 16 + lr];
                #pragma unroll
                for (int fi = 0; fi < 2; ++fi) cacc[fi][fj] = f32x4{bv, bv, bv, bv};
            }

            if (j != iw) {
                const ushort* __restrict__ AiL = &aggL[t * 2 + iw][r0l + lr][lk];
                const ushort* __restrict__ Wd = wdt + wb + lr * 64 + lk;
                f32x4 dacc[2][4];
                #pragma unroll
                for (int fj = 0; fj < 4; ++fj) {
                    float bv = bdv[(rel * 2 + l) * 64 + fj * 16 + lr];
                    #pragma unroll
                    for (int fi = 0; fi < 2; ++fi) dacc[fi][fj] = f32x4{bv, bv, bv, bv};
                }
                #pragma unroll
                for (int k0 = 0; k0 < 64; k0 += 32) {
                    bf16x8 ajh[2], nih[2], wcf[4], wdf[4];
                    #pragma unroll
                    for (int fi = 0; fi < 2; ++fi) {
                        ajh[fi] = *(const bf16x8*)(AjL + fi * 16 * 72 + k0);
                        bf16x8 ih = *(const bf16x8*)(AiL + fi * 16 * 72 + k0);
                        #pragma unroll
                        for (int q = 0; q < 8; ++q) nih[fi][q] = ih[q] ^ (short)0x8000;
                    }
                    #pragma unroll
                    for (int fj = 0; fj < 4; ++fj) {
                        wcf[fj] = *(const bf16x8*)(Wc + fj * 1024 + k0);
                        wdf[fj] = *(const bf16x8*)(Wd + fj * 1024 + k0);
                    }
                    #pragma unroll
                    for (int fi = 0; fi < 2; ++fi)
                        #pragma unroll
                        for (int fj = 0; fj < 4; ++fj) {
                            cacc[fi][fj] = __builtin_amdgcn_mfma_f32_16x16x32_bf16(ajh[fi], wcf[fj], cacc[fi][fj], 0, 0, 0);
                            dacc[fi][fj] = __builtin_amdgcn_mfma_f32_16x16x32_bf16(ajh[fi], wdf[fj], dacc[fi][fj], 0, 0, 0);
                            dacc[fi][fj] = __builtin_amdgcn_mfma_f32_16x16x32_bf16(nih[fi], wdf[fj], dacc[fi][fj], 0, 0, 0);
                        }
                }
                #pragma unroll
                for (int fi = 0; fi < 2; ++fi)
                    #pragma unroll
                    for (int fj = 0; fj < 4; ++fj)
                        #pragma unroll
                        for (int reg = 0; reg < 4; ++reg) {
                            hacc[fi][fj][reg] += fmaxf(cacc[fi][fj][reg], 0.f);
                            hacc[fi][fj][reg] += fast_tanh(dacc[fi][fj][reg]);
                        }
            } else {
                #pragma unroll
                for (int k0 = 0; k0 < 64; k0 += 32) {
                    bf16x8 ajh[2], wcf[4];
                    #pragma unroll
                    for (int fi = 0; fi < 2; ++fi)
                        ajh[fi] = *(const bf16x8*)(AjL + fi * 16 * 72 + k0);
                    #pragma unroll
                    for (int fj = 0; fj < 4; ++fj)
                        wcf[fj] = *(const bf16x8*)(Wc + fj * 1024 + k0);
                    #pragma unroll
                    for (int fi = 0; fi < 2; ++fi)
                        #pragma unroll
                        for (int fj = 0; fj < 4; ++fj)
                            cacc[fi][fj] = __builtin_amdgcn_mfma_f32_16x16x32_bf16(ajh[fi], wcf[fj], cacc[fi][fj], 0, 0, 0);
                }
                #pragma unroll
                for (int fj = 0; fj < 4; ++fj) {
                    float tb = fast_tanh(bdv[(rel * 2 + l) * 64 + fj * 16 + lr]);
                    #pragma unroll
                    for (int fi = 0; fi < 2; ++fi)
                        #pragma unroll
                        for (int reg = 0; reg < 4; ++reg) {
                            hacc[fi][fj][reg] += fmaxf(cacc[fi][fj][reg], 0.f);
                            hacc[fi][fj][reg] += tb;
                        }
                }
            }
        }
    }
    __syncthreads();   // all phase-2 LDS reads done; aggL reusable

    // ---- phase 3: transposed epilogue via LDS overlay ----
    float* stg = ((float*)aggL) + w * 2080;   // 32 x 65 fp32 per wave
    #pragma unroll
    for (int fi = 0; fi < 2; ++fi)
        #pragma unroll
        for (int reg = 0; reg < 4; ++reg) {
            int rloc = fi * 16 + (lane >> 4) * 4 + reg;
            bool ok = (n0 + r0l + rloc) < N_;
            #pragma unroll
            for (int fj = 0; fj < 4; ++fj)
                stg[rloc * 65 + fj * 16 + lr] = ok ? hacc[fi][fj][reg] : 0.f;
        }
    // same-wave LDS raw: ds ops in-order per wave
    ushort* __restrict__ Xb = xsb_out + (size_t)iw * MND_;
    int gbase = m * 500 + n0 + r0l;
    #pragma unroll
    for (int q = 0; q < 32; ++q) {
        if (n0 + r0l + q < N_)
            Xb[(size_t)(gbase + q) * 64 + lane] = to_bf16u(stg[q * 65 + lane]);
    }
    if (write_xt) {
        size_t tb = ((size_t)(iw * 96 + m) * 64 + lane) * 512 + n0 + r0l;
        #pragma unroll
        for (int g2 = 0; g2 < 4; ++g2) {
            short8 hv;
            #pragma unroll
            for (int q = 0; q < 8; ++q)
                hv[q] = (short)to_bf16u(stg[(g2 * 8 + q) * 65 + lane]);
            *(short8*)(xt_out + tb + g2 * 8) = hv;
        }
    }
}

// ---------------- K5: summarize — pair-channel gather, bf16 LDS staging (r19/20 proven) ----------------
__global__ __launch_bounds__(192) void summarize(
        const ushort* __restrict__ XSB, const int* __restrict__ nbr,
        const float* __restrict__ nw, float* __restrict__ out) {
    int wg = (blockIdx.x & 7) * 252 + (blockIdx.x >> 3);
    int grp = wg / 126;
    int rem = wg % 126;
    int i = grp >> 3, b = grp & 7;
    int l = rem / 42;
    int rem2 = rem % 42;
    int t = rem2 / 21;
    int tile = rem2 % 21;
    int n0 = tile * 24;
    int tid = threadIdx.x;
    int g6 = tid >> 5;           // node group 0..5
    int d2 = tid & 31;           // channel pair

    __shared__ int    nb_s[24][20];
    __shared__ float  w_s[24][20];
    __shared__ ushort staged[64][145];   // 18.6 KB bf16

    for (int e = tid; e < 480; e += 192) {
        int nn = e / 20, k = e % 20;
        int n = n0 + nn;
        nb_s[nn][k] = (n < N_) ? nbr[((size_t)t * N_ + n) * K_ + k] : 0;
        w_s[nn][k]  = (n < N_) ? nw[((size_t)t * N_ + n) * K_ + k] : 0.f;
    }
    __syncthreads();

    const uint* __restrict__ Xbase = (const uint*)(XSB + ((size_t)l * 2 + i) * MND_
                                     + (size_t)b * T_ * N_ * D_) + d2;
    size_t obase = ((size_t)((i * 8 + b) * 384 + t * 192 + l * 64)) * 6000
                 + (size_t)n0 * 12;

    #pragma unroll
    for (int half = 0; half < 2; ++half) {
        #pragma unroll
        for (int nn2 = 0; nn2 < 2; ++nn2) {
            int pl = g6 * 2 + nn2;
            int nl = half * 12 + pl;
            #pragma unroll
            for (int tt0 = 0; tt0 < 12; tt0 += 4) {
                const uint* __restrict__ Xm0 = Xbase + (size_t)(tt0 + 0) * 16000;
                const uint* __restrict__ Xm1 = Xbase + (size_t)(tt0 + 1) * 16000;
                const uint* __restrict__ Xm2 = Xbase + (size_t)(tt0 + 2) * 16000;
                const uint* __restrict__ Xm3 = Xbase + (size_t)(tt0 + 3) * 16000;
                float a0l = 0.f, a0h = 0.f, a1l = 0.f, a1h = 0.f;
                float a2l = 0.f, a2h = 0.f, a3l = 0.f, a3h = 0.f;
                #pragma unroll
                for (int k = 0; k < K_; ++k) {
                    size_t off = (size_t)nb_s[nl][k] * 32;
                    float w = w_s[nl][k];
                    uint u0 = Xm0[off], u1 = Xm1[off], u2 = Xm2[off], u3 = Xm3[off];
                    a0l = fmaf(__uint_as_float(u0 << 16), w, a0l);
                    a0h = fmaf(__uint_as_float(u0 & 0xffff0000u), w, a0h);
                    a1l = fmaf(__uint_as_float(u1 << 16), w, a1l);
                    a1h = fmaf(__uint_as_float(u1 & 0xffff0000u), w, a1h);
                    a2l = fmaf(__uint_as_float(u2 << 16), w, a2l);
                    a2h = fmaf(__uint_as_float(u2 & 0xffff0000u), w, a2h);
                    a3l = fmaf(__uint_as_float(u3 << 16), w, a3l);
                    a3h = fmaf(__uint_as_float(u3 & 0xffff0000u), w, a3h);
                }
                int p = pl * 12 + tt0;
                staged[2 * d2 + 0][p + 0] = to_bf16u(a0l);  staged[2 * d2 + 1][p + 0] = to_bf16u(a0h);
                staged[2 * d2 + 0][p + 1] = to_bf16u(a1l);  staged[2 * d2 + 1][p + 1] = to_bf16u(a1h);
                staged[2 * d2 + 0][p + 2] = to_bf16u(a2l);  staged[2 * d2 + 1][p + 2] = to_bf16u(a2h);
                staged[2 * d2 + 0][p + 3] = to_bf16u(a3l);  staged[2 * d2 + 1][p + 3] = to_bf16u(a3h);
            }
        }
        __syncthreads();
        int base_n = n0 + half * 12;
        int plim = (N_ - base_n) * 12;
        if (plim > 144) plim = 144;
        if (plim > 0) {
            for (int it = 0; it < 48; ++it) {
                int e = it * 192 + tid;
                int c2 = e / 144, q = e % 144;
                if (q < plim)
                    out[obase + (size_t)c2 * 6000 + (size_t)half * 144 + q] =
                        __uint_as_float((uint)staged[c2][q] << 16);
            }
        }
        __syncthreads();
    }
}

extern "C" void kernel_launch(void* const* d_in, const int* in_sizes, int n_in,
                              void* d_out, int out_size, void* d_ws, size_t ws_size,
                              hipStream_t stream) {
    const float* x0     = (const float*)d_in[0];
    const float* x1     = (const float*)d_in[1];
    const float* graphs = (const float*)d_in[2];
    const int*   nbr    = (const int*)d_in[3];
    const float* nwt    = (const float*)d_in[4];
    const float* aw     = (const float*)d_in[5];
    const float* Bw     = (const float*)d_in[6];
    const float* ab     = (const float*)d_in[7];
    const float* Bb     = (const float*)d_in[8];
    float* out = (float*)d_out;
    float* ws  = (float*)d_ws;

    ushort* XSB = (ushort*)(ws + XSB_OFF);
    ushort* XTb = (ushort*)(ws + XTB_OFF);
    ushort* ATh = (ushort*)(ws + AT_HI_OFF);
    ushort* XTa = (ushort*)(ws + XT_OFF);
    ushort* WCT = (ushort*)(ws + WCT_OFF);
    ushort* WDT = (ushort*)(ws + WDT_OFF);
    float*  BC  = ws + BC_OFF;
    float*  BD  = ws + BD_OFF;

    fuse_weights<<<520, 256, 0, stream>>>(aw, Bw, ab, Bb, BC, BD, WCT, WDT);
    transpose_in<<<8000, 256, 0, stream>>>(x0, x1, XSB);
    adj_prep<<<dim3(16, 16, 2), 256, 0, stream>>>(graphs, ATh);
    xt_cast<<<dim3(8, 96, 2), 256, 0, stream>>>(XSB, XTa);
    agg_combine_mfma<<<dim3(8, 96), 256, 0, stream>>>(
        ATh, XTa, WCT, WDT, BC, BD, XSB + 2ul * MND_, XTb, 0, 1);
    agg_combine_mfma<<<dim3(8, 96), 256, 0, stream>>>(
        ATh, XTb, WCT, WDT, BC, BD, XSB + 4ul * MND_, XTb, 1, 0);
    summarize<<<2016, 192, 0, stream>>>(XSB, nbr, nwt, out);
}